// Round 16
// baseline (362.660 us; speedup 1.0000x reference)
//
#include <hip/hip_runtime.h>
#include <cstdint>
#include <cstddef>

#define DEVI __device__ __forceinline__
#define WAITVM0 asm volatile("s_waitcnt vmcnt(0)" ::: "memory")
#define WAITVM4 asm volatile("s_waitcnt vmcnt(4)" ::: "memory")
#define WAITVM8 asm volatile("s_waitcnt vmcnt(8)" ::: "memory")
#define WAITLGKM asm volatile("s_waitcnt lgkmcnt(0)" ::: "memory")
#define SCHEDB __builtin_amdgcn_sched_barrier(0)

typedef __bf16 bf16x8 __attribute__((ext_vector_type(8)));
typedef float f32x4 __attribute__((ext_vector_type(4)));
typedef uint32_t u32x4 __attribute__((ext_vector_type(4)));

// ---------- scalar helpers ----------
DEVI ushort f2bf(float f) {
  union { float f; uint32_t u; } v; v.f = f;
  uint32_t u = v.u;
  return (ushort)((u + 0x7FFFu + ((u >> 16) & 1u)) >> 16);  // RNE
}
DEVI float bf2f(ushort h) {
  union { uint32_t u; float f; } v; v.u = ((uint32_t)h) << 16;
  return v.f;
}
DEVI float lrelu(float t) { return t > 0.0f ? t : 0.1f * t; }

DEVI u32x4 cvt8(f32x4 a, f32x4 b) {  // 8 f32 -> 8 packed bf16
  u32x4 o;
  o[0] = (uint32_t)f2bf(a[0]) | ((uint32_t)f2bf(a[1]) << 16);
  o[1] = (uint32_t)f2bf(a[2]) | ((uint32_t)f2bf(a[3]) << 16);
  o[2] = (uint32_t)f2bf(b[0]) | ((uint32_t)f2bf(b[1]) << 16);
  o[3] = (uint32_t)f2bf(b[2]) | ((uint32_t)f2bf(b[3]) << 16);
  return o;
}
// GN+LeakyReLU on 8 packed bf16 with per-channel f32 coefs
DEVI u32x4 gn8(u32x4 d, f32x4 g0, f32x4 g1, f32x4 b0, f32x4 b1) {
  float f0 = bf2f((ushort)(d[0] & 0xffffu)), f1 = bf2f((ushort)(d[0] >> 16));
  float f2 = bf2f((ushort)(d[1] & 0xffffu)), f3 = bf2f((ushort)(d[1] >> 16));
  float f4 = bf2f((ushort)(d[2] & 0xffffu)), f5 = bf2f((ushort)(d[2] >> 16));
  float f6 = bf2f((ushort)(d[3] & 0xffffu)), f7 = bf2f((ushort)(d[3] >> 16));
  float t0 = lrelu(f0 * g0[0] + b0[0]), t1 = lrelu(f1 * g0[1] + b0[1]);
  float t2 = lrelu(f2 * g0[2] + b0[2]), t3 = lrelu(f3 * g0[3] + b0[3]);
  float t4 = lrelu(f4 * g1[0] + b1[0]), t5 = lrelu(f5 * g1[1] + b1[1]);
  float t6 = lrelu(f6 * g1[2] + b1[2]), t7 = lrelu(f7 * g1[3] + b1[3]);
  u32x4 o;
  o[0] = (uint32_t)f2bf(t0) | ((uint32_t)f2bf(t1) << 16);
  o[1] = (uint32_t)f2bf(t2) | ((uint32_t)f2bf(t3) << 16);
  o[2] = (uint32_t)f2bf(t4) | ((uint32_t)f2bf(t5) << 16);
  o[3] = (uint32_t)f2bf(t6) | ((uint32_t)f2bf(t7) << 16);
  return o;
}

// async global->LDS, 16B/lane; LDS dest is wave-uniform base.
DEVI void async_copy16(const void* g, void* l) {
  __attribute__((address_space(1))) void* gp =
      reinterpret_cast<__attribute__((address_space(1))) void*>(
          reinterpret_cast<uintptr_t>(const_cast<void*>(g)));
  __attribute__((address_space(3))) void* lp =
      reinterpret_cast<__attribute__((address_space(3))) void*>(
          static_cast<uint32_t>(reinterpret_cast<uintptr_t>(l)));
  __builtin_amdgcn_global_load_lds(gp, lp, 16, 0, 0);
}

// ---------- f32->bf16 conversion, WEIGHTS only (4 segments) ----------
struct CvtSeg { const f32x4* src; u32x4* dst; };
struct CvtArgs { CvtSeg seg[4]; int start[5]; };

__global__ void cvt_multi(CvtArgs a, int total8) {
  int i = blockIdx.x * blockDim.x + threadIdx.x;
  const int stride = gridDim.x * blockDim.x;
  for (; i < total8; i += stride) {
    int s = 0;
#pragma unroll
    for (int j = 1; j < 4; ++j) s += (i >= a.start[j]);
    const int off = i - a.start[s];
    f32x4 f0 = a.seg[s].src[off * 2];
    f32x4 f1 = a.seg[s].src[off * 2 + 1];
    a.seg[s].dst[off] = cvt8(f0, f1);
  }
}

__global__ void zero_kernel(float* __restrict__ p) { p[threadIdx.x] = 0.0f; }

// ---------- GN+LeakyReLU apply with inline coef computation ----------
__global__ void gn_apply(const ushort* __restrict__ x, const float* __restrict__ stats,
                         const float* __restrict__ gamma, const float* __restrict__ beta,
                         ushort* __restrict__ y, int Nrows, int C, float invcnt) {
  const int tpr = C >> 3;  // threads per row
  const int gtid = blockIdx.x * blockDim.x + threadIdx.x;
  const int c8 = (gtid % tpr) * 8;
  const int g = c8 / (C >> 5);
  const float mean = stats[2 * g] * invcnt;
  const float var = stats[2 * g + 1] * invcnt - mean * mean;
  const float inv = rsqrtf(var + 1e-5f);
  const f32x4 gm0 = *(const f32x4*)(gamma + c8), gm1 = *(const f32x4*)(gamma + c8 + 4);
  const f32x4 bt0 = *(const f32x4*)(beta + c8),  bt1 = *(const f32x4*)(beta + c8 + 4);
  f32x4 g0, g1, b0, b1;
#pragma unroll
  for (int j = 0; j < 4; ++j) {
    g0[j] = gm0[j] * inv; b0[j] = bt0[j] - mean * g0[j];
    g1[j] = gm1[j] * inv; b1[j] = bt1[j] - mean * g1[j];
  }
  const int rstep = (gridDim.x * blockDim.x) / tpr;
  for (int r = gtid / tpr; r < Nrows; r += rstep) {
    u32x4 d = *(const u32x4*)(x + (size_t)r * C + c8);
    *(u32x4*)(y + (size_t)r * C + c8) = gn8(d, g0, g1, b0, b1);
  }
}

// ---------- 4-wave single-buffer GEMM: BM=128 x BN=128 x BK=64 ----------
// Round-8 proven K-loop (stage -> barrier -> compute -> barrier; TLP-hidden).
// A-tile modes per K-tile t:
//   t <  ng, GREG=0: bf16 gather rows via global_load_lds DMA (4 glds).
//   t <  ng, GREG=1: bf16 gather rows reg-staged ONE TILE AHEAD (4 x 16B loads
//        as f32x4 bit-patterns into rdv[0..3], plain ds_write at stage top) —
//        covers LLC-latency gather sources (l2: l3b = 67 MB > L2) with a full
//        compute phase of issue->consume distance. No VALU in the consume
//        (r11's failure was gn8+coef-LDS there, not reg-staging).
//   t >= ng: direct f32 feats reg-staged one tile ahead + cvt8 (T14, as r8).
// Wait discipline (uniform): mid WAITVM4 retires reg(t) (only B(t)'s 4 glds
// younger); end WAITVM(nreg(t+1)) with nreg in {0,4,8} -> all tile-t glds
// landed, tile-t+1 reg loads stay in flight. launch_bounds(256,3) -> VGPR ~84,
// no spills (r12/r14 lesson: never force VGPR below the accumulators' need).
// T2 swizzle (conflicts == 0, verified r3-r15) + XCD-bijective bid swizzle.
template <int EPI, int STATS, int GREG>
__global__ __launch_bounds__(256, 3) void gemms(
    const ushort* __restrict__ Ag, const float* __restrict__ Adf,
    const int* __restrict__ up, int dg,
    const ushort* __restrict__ Bw, const float* __restrict__ bias,
    void* __restrict__ Cout, float* __restrict__ stats,
    int M, int N, int K) {
  constexpr int BM = 128, BN = 128, BK = 64;
  constexpr int ABY = BM * BK * 2;        // 16384
  __shared__ __align__(16) char smem[ABY + BN * BK * 2];  // 32 KB single buffer
  __shared__ int s_up[BM];
  __shared__ float ssum[32], ssq[32];

  const int nbn = N >> 7;
  const int cpx = (int)gridDim.x >> 3;   // grids are multiples of 8
  const int bid = ((int)blockIdx.x & 7) * cpx + ((int)blockIdx.x >> 3);
  const int bm = bid / nbn, bn = bid % nbn;
  const int row0 = bm * BM, col0 = bn * BN;
  const int tid = threadIdx.x, lane = tid & 63, wave = tid >> 6;
  const int wm = wave >> 1, wn = wave & 1;   // 2M x 2N waves: 64x64 out each
  const int dd = K - dg;
  const int ng = dg / BK;
  const int nt = K / BK;

  if (up != nullptr && tid < BM) s_up[tid] = up[row0 + tid];
  if constexpr (STATS) { if (tid < 32) { ssum[tid] = 0.f; ssq[tid] = 0.f; } }
  __syncthreads();  // drains counters -> clean vmcnt baseline

  // staging geometry: 4 A-chunks + 4 B-chunks of 16B per thread
  int cs_[4];
  const ushort* pG[4]; const float* pD[4];
#pragma unroll
  for (int li = 0; li < 4; ++li) {
    const int chunk = li * 256 + tid;
    const int r = chunk >> 3;                       // 0..127
    cs_[li] = ((chunk & 7) ^ (r & 7)) << 3;
    pG[li] = (ng > 0) ? (Ag + (size_t)s_up[r] * dg + cs_[li]) : nullptr;
    pD[li] = (ng < nt) ? (Adf + (size_t)(row0 + r) * dd + cs_[li]) : nullptr;
  }
  const ushort* pB[4];
#pragma unroll
  for (int li = 0; li < 4; ++li) {
    const int chunk = li * 256 + tid;
    const int rb = chunk >> 3;                      // 0..127
    pB[li] = Bw + (size_t)(col0 + rb) * K + (((chunk & 7) ^ (rb & 7)) << 3);
  }

  f32x4 rdv[8];  // reg-staged A data for tile t (issued at stage(t-1), T14).
                 // Gather tiles (GREG) use rdv[0..3] as raw 16B bf16 payloads.

  auto isReg = [&](int t) -> bool {
    return (t < ng) ? (GREG != 0) : true;
  };
  auto nregv = [&](int t) -> int {
    if (t >= nt) return 0;
    if (t < ng) return GREG ? 4 : 0;
    return 8;
  };
  auto issueAg = [&](int t) {   // glds gather (GREG=0 only)
#pragma unroll
    for (int li = 0; li < 4; ++li)
      async_copy16(pG[li] + t * BK, smem + li * 4096 + wave * 1024);
  };
  auto issueB = [&](int t) {
#pragma unroll
    for (int li = 0; li < 4; ++li)
      async_copy16(pB[li] + t * BK, smem + ABY + li * 4096 + wave * 1024);
  };
  auto issueReg = [&](int t) {
    if (GREG && t < ng) {
      const int k0 = t * BK;
#pragma unroll
      for (int li = 0; li < 4; ++li)
        rdv[li] = *(const f32x4*)(const void*)(pG[li] + k0);  // raw 16B bf16
    } else {
      const int kd = t * BK - dg;
#pragma unroll
      for (int li = 0; li < 4; ++li) {
        rdv[2 * li]     = *(const f32x4*)(pD[li] + kd);
        rdv[2 * li + 1] = *(const f32x4*)(pD[li] + kd + 4);
      }
    }
  };
  auto dsWrite = [&](int t) {
    if (GREG && t < ng) {
#pragma unroll
      for (int li = 0; li < 4; ++li)
        *(f32x4*)(smem + li * 4096 + tid * 16) = rdv[li];     // plain 16B copy
    } else {
#pragma unroll
      for (int li = 0; li < 4; ++li)
        *(u32x4*)(smem + li * 4096 + tid * 16) = cvt8(rdv[2 * li], rdv[2 * li + 1]);
    }
  };

  // ds_read fragment byte offsets (loop-invariant, swizzled)
  int offA[2][4], offB[2][4];
#pragma unroll
  for (int kk = 0; kk < 2; ++kk) {
    const int ch = kk * 4 + (lane >> 4);
#pragma unroll
    for (int m = 0; m < 4; ++m) {
      const int ra = wm * 64 + m * 16 + (lane & 15);
      offA[kk][m] = ra * 128 + ((ch ^ (ra & 7)) << 4);
    }
#pragma unroll
    for (int n = 0; n < 4; ++n) {
      const int rb = wn * 64 + n * 16 + (lane & 15);
      offB[kk][n] = ABY + rb * 128 + ((ch ^ (rb & 7)) << 4);
    }
  }

  if (isReg(0)) issueReg(0);   // prologue: tile-0 reg loads in flight

  f32x4 acc[4][4] = {};
  for (int t = 0; t < nt; ++t) {
    const bool curR = isReg(t);
    // ---- stage phase (buf free) ----
    if (!curR) issueAg(t);                 // 4 glds (GREG=0 gather tile)
    issueB(t);                             // 4 glds
    if (curR) {
      WAITVM4;                             // reg(t) retired; B(t) 4 glds in flight
      SCHEDB;
      dsWrite(t);                          // copy/cvt8 + 4 ds_write_b128
    }
    const int nr1 = nregv(t + 1);
    if (nr1) issueReg(t + 1);              // left in flight across compute (T14)
    if (nr1 == 8)      { WAITVM8; }        // tile-t glds landed; 8 reg in flight
    else if (nr1 == 4) { WAITVM4; }        // tile-t glds landed; 4 reg in flight
    else               { WAITVM0; }
    WAITLGKM;                              // ds_writes visible
    SCHEDB;
    __builtin_amdgcn_s_barrier();
    // ---- compute phase ----
#pragma unroll
    for (int kk = 0; kk < 2; ++kk) {
      bf16x8 af[4], bv[4];
#pragma unroll
      for (int m = 0; m < 4; ++m) af[m] = *(const bf16x8*)(smem + offA[kk][m]);
#pragma unroll
      for (int n = 0; n < 4; ++n) bv[n] = *(const bf16x8*)(smem + offB[kk][n]);
      __builtin_amdgcn_s_setprio(1);
#pragma unroll
      for (int m = 0; m < 4; ++m)
#pragma unroll
        for (int n = 0; n < 4; ++n)
          acc[m][n] = __builtin_amdgcn_mfma_f32_16x16x32_bf16(af[m], bv[n], acc[m][n], 0, 0, 0);
      __builtin_amdgcn_s_setprio(0);
    }
    __builtin_amdgcn_s_barrier();
  }

  // --- epilogue: bias, store, optional fused group stats ---
  const int cr = (lane >> 4) << 2;
  const int cc = lane & 15;
  float sacc[4] = {0, 0, 0, 0}, qacc[4] = {0, 0, 0, 0};
#pragma unroll
  for (int n = 0; n < 4; ++n) {
    const int colg = col0 + wn * 64 + n * 16 + cc;
    const float bvv = bias[colg];
#pragma unroll
    for (int m = 0; m < 4; ++m) {
      const int rowg = row0 + wm * 64 + m * 16 + cr;
#pragma unroll
      for (int r2 = 0; r2 < 4; ++r2) {
        const float v = acc[m][n][r2] + bvv;
        if constexpr (STATS) { sacc[n] += v; qacc[n] += v * v; }
        if constexpr (EPI == 0)
          ((ushort*)Cout)[(size_t)(rowg + r2) * N + colg] = f2bf(v);
        else
          ((float*)Cout)[(size_t)(rowg + r2) * N + colg] = v;
      }
    }
  }
  if constexpr (STATS) {
    const int gsize = N >> 5;
#pragma unroll
    for (int n = 0; n < 4; ++n) {
      float s = sacc[n], q = qacc[n];
      s += __shfl_xor(s, 16); q += __shfl_xor(q, 16);
      s += __shfl_xor(s, 32); q += __shfl_xor(q, 32);
      if (lane < 16) {
        const int colg = col0 + wn * 64 + n * 16 + lane;
        const int g = colg / gsize;
        atomicAdd(&ssum[g], s);
        atomicAdd(&ssq[g], q);
      }
    }
    __syncthreads();
    if (tid < 32) {
      const int g0 = col0 / gsize, g1 = (col0 + BN) / gsize;
      if (tid >= g0 && tid < g1) {
        atomicAdd(&stats[2 * tid], ssum[tid]);
        atomicAdd(&stats[2 * tid + 1], ssq[tid]);
      }
    }
  }
}

// ---------- host ----------
extern "C" void kernel_launch(void* const* d_in, const int* in_sizes, int n_in,
                              void* d_out, int out_size, void* d_ws, size_t ws_size,
                              hipStream_t stream) {
  const float* s2   = (const float*)d_in[0];   // (131072, 256)
  const float* s3   = (const float*)d_in[1];   // (32768, 512)
  const float* s4   = (const float*)d_in[2];   // (8192, 1024)
  const float* s5   = (const float*)d_in[3];   // (2048, 2048)
  const int*   up1  = (const int*)d_in[4];
  const int*   up2  = (const int*)d_in[5];
  const int*   up3  = (const int*)d_in[6];
  const float* W_in = (const float*)d_in[7];   // (2048, 2048)
  const float* b_in = (const float*)d_in[8];
  const float* W4   = (const float*)d_in[9];   // (1024, 3072)
  const float* b4   = (const float*)d_in[10];
  const float* g4   = (const float*)d_in[11];
  const float* bt4  = (const float*)d_in[12];
  const float* W3   = (const float*)d_in[13];  // (512, 1536)
  const float* b3   = (const float*)d_in[14];
  const float* g3   = (const float*)d_in[15];
  const float* bt3  = (const float*)d_in[16];
  const float* W2   = (const float*)d_in[17];  // (256, 768)
  const float* b2   = (const float*)d_in[18];
  float* out = (float*)d_out;
  char* ws = (char*)d_ws;

  // Workspace layout (~126 MB)
  ushort* Winb  = (ushort*)(ws + 0);          //  8.39 MB
  ushort* W4b   = (ushort*)(ws + 8388608);    //  6.29 MB
  ushort* W3b   = (ushort*)(ws + 14680064);   //  1.57 MB
  ushort* W2b   = (ushort*)(ws + 16252928);   //  0.39 MB
  float*  stats = (float*)(ws + 16646144);    //  512 B
  ushort* x5b   = (ushort*)(ws + 16777216);   //  8.39 MB (2048x2048)
  ushort* l4lin = (ushort*)(ws + 25165824);   // 16.78 MB (8192x1024)
  ushort* l4b   = (ushort*)(ws + 41943040);   // 16.78 MB
  ushort* l3lin = (ushort*)(ws + 58720256);   // 33.55 MB (32768x512)
  ushort* l3b   = (ushort*)(ws + 92274688);   // 33.55 MB

  zero_kernel<<<1, 128, 0, stream>>>(stats);

  // convert weights only
  CvtArgs ca;
  const float* srcs[4] = { W_in, W4, W3, W2 };
  ushort* dsts[4] = { Winb, W4b, W3b, W2b };
  long ns[4] = { 2048L*2048, 1024L*3072, 512L*1536, 256L*768 };
  int cum = 0;
  for (int i = 0; i < 4; ++i) {
    ca.seg[i].src = (const f32x4*)srcs[i];
    ca.seg[i].dst = (u32x4*)dsts[i];
    ca.start[i] = cum;
    cum += (int)(ns[i] >> 3);
  }
  ca.start[4] = cum;
  cvt_multi<<<1024, 256, 0, stream>>>(ca, cum);

  // x5 = s5(f32 direct) @ W_in^T + b_in (2048x2048, K=2048)  grid 16x16=256
  gemms<0, 0, 0><<<256, 256, 0, stream>>>(
      nullptr, s5, nullptr, 0, Winb, b_in, x5b, nullptr, 2048, 2048, 2048);
  // l4lin = concat(x5b[up3] DMA, s4 f32) @ W4^T + b4, stats fused (8192x1024,K=3072)
  // gather source x5b is L2-resident -> keep glds DMA (GREG=0)
  gemms<0, 1, 0><<<512, 256, 0, stream>>>(
      x5b, s4, up3, 2048, W4b, b4, l4lin, stats, 8192, 1024, 3072);
  gn_apply<<<2048, 256, 0, stream>>>(l4lin, stats, g4, bt4, l4b, 8192, 1024,
                                     1.0f / 262144.0f);
  // l3lin = concat(l4b[up2] DMA, s3 f32) @ W3^T + b3, stats fused (32768x512,K=1536)
  gemms<0, 1, 0><<<1024, 256, 0, stream>>>(
      l4b, s3, up2, 1024, W3b, b3, l3lin, stats + 64, 32768, 512, 1536);
  gn_apply<<<2048, 256, 0, stream>>>(l3lin, stats + 64, g3, bt3, l3b, 32768, 512,
                                     1.0f / 524288.0f);
  // out = concat(l3b[up1] reg-staged (GREG=1: l3b 67MB > L2, LLC-latency gather),
  // s2 f32) @ W2^T + b2 -> f32 (131072x256, K=768) grid 1024x2=2048
  gemms<1, 0, 1><<<2048, 256, 0, stream>>>(
      l3b, s2, up1, 512, W2b, b2, out, nullptr, 131072, 256, 768);

  (void)in_sizes; (void)n_in; (void)out_size; (void)ws_size;
}

// Round 17
// 320.288 us; speedup vs baseline: 1.1323x; 1.1323x over previous
//
#include <hip/hip_runtime.h>
#include <cstdint>
#include <cstddef>

#define DEVI __device__ __forceinline__
#define WAITVM0 asm volatile("s_waitcnt vmcnt(0)" ::: "memory")
#define WAITVM4 asm volatile("s_waitcnt vmcnt(4)" ::: "memory")
#define WAITVM8 asm volatile("s_waitcnt vmcnt(8)" ::: "memory")
#define WAITLGKM asm volatile("s_waitcnt lgkmcnt(0)" ::: "memory")
#define SCHEDB __builtin_amdgcn_sched_barrier(0)

typedef __bf16 bf16x8 __attribute__((ext_vector_type(8)));
typedef float f32x4 __attribute__((ext_vector_type(4)));
typedef uint32_t u32x4 __attribute__((ext_vector_type(4)));

// ---------- scalar helpers ----------
DEVI ushort f2bf(float f) {
  union { float f; uint32_t u; } v; v.f = f;
  uint32_t u = v.u;
  return (ushort)((u + 0x7FFFu + ((u >> 16) & 1u)) >> 16);  // RNE
}
DEVI float bf2f(ushort h) {
  union { uint32_t u; float f; } v; v.u = ((uint32_t)h) << 16;
  return v.f;
}
DEVI float lrelu(float t) { return t > 0.0f ? t : 0.1f * t; }

DEVI u32x4 cvt8(f32x4 a, f32x4 b) {  // 8 f32 -> 8 packed bf16
  u32x4 o;
  o[0] = (uint32_t)f2bf(a[0]) | ((uint32_t)f2bf(a[1]) << 16);
  o[1] = (uint32_t)f2bf(a[2]) | ((uint32_t)f2bf(a[3]) << 16);
  o[2] = (uint32_t)f2bf(b[0]) | ((uint32_t)f2bf(b[1]) << 16);
  o[3] = (uint32_t)f2bf(b[2]) | ((uint32_t)f2bf(b[3]) << 16);
  return o;
}
// GN+LeakyReLU on 8 packed bf16 with per-channel f32 coefs
DEVI u32x4 gn8(u32x4 d, f32x4 g0, f32x4 g1, f32x4 b0, f32x4 b1) {
  float f0 = bf2f((ushort)(d[0] & 0xffffu)), f1 = bf2f((ushort)(d[0] >> 16));
  float f2 = bf2f((ushort)(d[1] & 0xffffu)), f3 = bf2f((ushort)(d[1] >> 16));
  float f4 = bf2f((ushort)(d[2] & 0xffffu)), f5 = bf2f((ushort)(d[2] >> 16));
  float f6 = bf2f((ushort)(d[3] & 0xffffu)), f7 = bf2f((ushort)(d[3] >> 16));
  float t0 = lrelu(f0 * g0[0] + b0[0]), t1 = lrelu(f1 * g0[1] + b0[1]);
  float t2 = lrelu(f2 * g0[2] + b0[2]), t3 = lrelu(f3 * g0[3] + b0[3]);
  float t4 = lrelu(f4 * g1[0] + b1[0]), t5 = lrelu(f5 * g1[1] + b1[1]);
  float t6 = lrelu(f6 * g1[2] + b1[2]), t7 = lrelu(f7 * g1[3] + b1[3]);
  u32x4 o;
  o[0] = (uint32_t)f2bf(t0) | ((uint32_t)f2bf(t1) << 16);
  o[1] = (uint32_t)f2bf(t2) | ((uint32_t)f2bf(t3) << 16);
  o[2] = (uint32_t)f2bf(t4) | ((uint32_t)f2bf(t5) << 16);
  o[3] = (uint32_t)f2bf(t6) | ((uint32_t)f2bf(t7) << 16);
  return o;
}

// async global->LDS, 16B/lane; LDS dest is wave-uniform base.
DEVI void async_copy16(const void* g, void* l) {
  __attribute__((address_space(1))) void* gp =
      reinterpret_cast<__attribute__((address_space(1))) void*>(
          reinterpret_cast<uintptr_t>(const_cast<void*>(g)));
  __attribute__((address_space(3))) void* lp =
      reinterpret_cast<__attribute__((address_space(3))) void*>(
          static_cast<uint32_t>(reinterpret_cast<uintptr_t>(l)));
  __builtin_amdgcn_global_load_lds(gp, lp, 16, 0, 0);
}

// ---------- f32->bf16 conversion, WEIGHTS only (4 segments) ----------
struct CvtSeg { const f32x4* src; u32x4* dst; };
struct CvtArgs { CvtSeg seg[4]; int start[5]; };

__global__ void cvt_multi(CvtArgs a, int total8) {
  int i = blockIdx.x * blockDim.x + threadIdx.x;
  const int stride = gridDim.x * blockDim.x;
  for (; i < total8; i += stride) {
    int s = 0;
#pragma unroll
    for (int j = 1; j < 4; ++j) s += (i >= a.start[j]);
    const int off = i - a.start[s];
    f32x4 f0 = a.seg[s].src[off * 2];
    f32x4 f1 = a.seg[s].src[off * 2 + 1];
    a.seg[s].dst[off] = cvt8(f0, f1);
  }
}

__global__ void zero_kernel(float* __restrict__ p) { p[threadIdx.x] = 0.0f; }

// ---------- GN+LeakyReLU apply with inline coef computation ----------
// y = lrelu((x - mean)/sqrt(var+eps) * gamma + beta), coefs derived per-thread
// from the fused GEMM stats (all 8 channels of a thread lie in one group since
// group size = C/32 >= 16 and c8 is 8-aligned). Replaces gn_coef + gn_apply.
__global__ void gn_apply(const ushort* __restrict__ x, const float* __restrict__ stats,
                         const float* __restrict__ gamma, const float* __restrict__ beta,
                         ushort* __restrict__ y, int Nrows, int C, float invcnt) {
  const int tpr = C >> 3;  // threads per row
  const int gtid = blockIdx.x * blockDim.x + threadIdx.x;
  const int c8 = (gtid % tpr) * 8;
  const int g = c8 / (C >> 5);
  const float mean = stats[2 * g] * invcnt;
  const float var = stats[2 * g + 1] * invcnt - mean * mean;
  const float inv = rsqrtf(var + 1e-5f);
  const f32x4 gm0 = *(const f32x4*)(gamma + c8), gm1 = *(const f32x4*)(gamma + c8 + 4);
  const f32x4 bt0 = *(const f32x4*)(beta + c8),  bt1 = *(const f32x4*)(beta + c8 + 4);
  f32x4 g0, g1, b0, b1;
#pragma unroll
  for (int j = 0; j < 4; ++j) {
    g0[j] = gm0[j] * inv; b0[j] = bt0[j] - mean * g0[j];
    g1[j] = gm1[j] * inv; b1[j] = bt1[j] - mean * g1[j];
  }
  const int rstep = (gridDim.x * blockDim.x) / tpr;
  for (int r = gtid / tpr; r < Nrows; r += rstep) {
    u32x4 d = *(const u32x4*)(x + (size_t)r * C + c8);
    *(u32x4*)(y + (size_t)r * C + c8) = gn8(d, g0, g1, b0, b1);
  }
}

// ---------- 4-wave single-buffer GEMM: BM=128 x BN=128 x BK=64 ----------
// Round-8 proven structure (best measured: 320.3 us total), kept verbatim.
// Latency hidden by TLP; stage -> barrier -> compute -> barrier per K-tile.
// A row r = [ bf16 gather rows Ag[up[r]] (dg cols, pure global_load_lds DMA) |
// direct f32 feats row r (reg-staged one tile ahead + cvt8 -> ds_write, T14) ].
// Per K-tile: {A-glds | B-glds | mid vmcnt(4): rdv(t) retired -> ds_write cvt8 |
// issue rdv(t+1) | vmcnt(8 if rdv in flight else 0) | lgkm | barrier | 16 ds_read
// + 32 MFMA | barrier}. launch_bounds(256,3) -> VGPR 84, no spills. CLOSED
// experiment families (all regressed): pipeline depth (r9), wider tiles (r10),
// GN fusion into GEMM (r5/r11/r14), VGPR forcing (r12/r14), reg-staged gather
// (r5/r11/r16). T2 swizzle: conflicts == 0 verified throughout. XCD swizzle.
template <int EPI, int STATS>
__global__ __launch_bounds__(256, 3) void gemms(
    const ushort* __restrict__ Ag, const float* __restrict__ Adf,
    const int* __restrict__ up, int dg,
    const ushort* __restrict__ Bw, const float* __restrict__ bias,
    void* __restrict__ Cout, float* __restrict__ stats,
    int M, int N, int K) {
  constexpr int BM = 128, BN = 128, BK = 64;
  constexpr int ABY = BM * BK * 2;        // 16384
  __shared__ __align__(16) char smem[ABY + BN * BK * 2];  // 32 KB single buffer
  __shared__ int s_up[BM];
  __shared__ float ssum[32], ssq[32];

  const int nbn = N >> 7;
  const int cpx = (int)gridDim.x >> 3;   // grids are multiples of 8
  const int bid = ((int)blockIdx.x & 7) * cpx + ((int)blockIdx.x >> 3);
  const int bm = bid / nbn, bn = bid % nbn;
  const int row0 = bm * BM, col0 = bn * BN;
  const int tid = threadIdx.x, lane = tid & 63, wave = tid >> 6;
  const int wm = wave >> 1, wn = wave & 1;   // 2M x 2N waves: 64x64 out each
  const int dd = K - dg;
  const int ng = dg / BK;
  const int nt = K / BK;

  if (up != nullptr && tid < BM) s_up[tid] = up[row0 + tid];
  if constexpr (STATS) { if (tid < 32) { ssum[tid] = 0.f; ssq[tid] = 0.f; } }
  __syncthreads();  // drains counters -> clean vmcnt baseline

  // staging geometry: 4 A-chunks + 4 B-chunks of 16B per thread
  int cs_[4];
  const ushort* pG[4]; const float* pD[4];
#pragma unroll
  for (int li = 0; li < 4; ++li) {
    const int chunk = li * 256 + tid;
    const int r = chunk >> 3;                       // 0..127
    cs_[li] = ((chunk & 7) ^ (r & 7)) << 3;
    pG[li] = (ng > 0) ? (Ag + (size_t)s_up[r] * dg + cs_[li]) : nullptr;
    pD[li] = (ng < nt) ? (Adf + (size_t)(row0 + r) * dd + cs_[li]) : nullptr;
  }
  const ushort* pB[4];
#pragma unroll
  for (int li = 0; li < 4; ++li) {
    const int chunk = li * 256 + tid;
    const int rb = chunk >> 3;                      // 0..127
    pB[li] = Bw + (size_t)(col0 + rb) * K + (((chunk & 7) ^ (rb & 7)) << 3);
  }

  f32x4 rdv[8];  // direct-f32 regs for tile t (issued at stage(t-1), T14)

  auto issueAg = [&](int t) {
#pragma unroll
    for (int li = 0; li < 4; ++li)
      async_copy16(pG[li] + t * BK, smem + li * 4096 + wave * 1024);
  };
  auto issueB = [&](int t) {
#pragma unroll
    for (int li = 0; li < 4; ++li)
      async_copy16(pB[li] + t * BK, smem + ABY + li * 4096 + wave * 1024);
  };
  auto issueRdv = [&](int t) {
    const int kd = t * BK - dg;
#pragma unroll
    for (int li = 0; li < 4; ++li) {
      rdv[2 * li]     = *(const f32x4*)(pD[li] + kd);
      rdv[2 * li + 1] = *(const f32x4*)(pD[li] + kd + 4);
    }
  };
  auto dsWrite = [&]() {
#pragma unroll
    for (int li = 0; li < 4; ++li)
      *(u32x4*)(smem + li * 4096 + tid * 16) = cvt8(rdv[2 * li], rdv[2 * li + 1]);
  };

  // ds_read fragment byte offsets (loop-invariant, swizzled)
  int offA[2][4], offB[2][4];
#pragma unroll
  for (int kk = 0; kk < 2; ++kk) {
    const int ch = kk * 4 + (lane >> 4);
#pragma unroll
    for (int m = 0; m < 4; ++m) {
      const int ra = wm * 64 + m * 16 + (lane & 15);
      offA[kk][m] = ra * 128 + ((ch ^ (ra & 7)) << 4);
    }
#pragma unroll
    for (int n = 0; n < 4; ++n) {
      const int rb = wn * 64 + n * 16 + (lane & 15);
      offB[kk][n] = ABY + rb * 128 + ((ch ^ (rb & 7)) << 4);
    }
  }

  if (ng == 0) issueRdv(0);   // prologue: rdv(0) in flight (invariant for t=0)

  f32x4 acc[4][4] = {};
  for (int t = 0; t < nt; ++t) {
    const bool curD = (t >= ng);
    const bool nxtDirect = (t + 1 < nt) && (t + 1 >= ng);
    // ---- stage phase (buf free) ----
    if (!curD) issueAg(t);                 // 4 glds
    issueB(t);                             // 4 glds
    if (curD) {
      WAITVM4;                             // rdv(t) retired; 4 B-glds in flight
      SCHEDB;
      dsWrite();                           // cvt8 + 4 ds_write_b128
    }
    if (nxtDirect) issueRdv(t + 1);        // 8 loads, left in flight (T14)
    if (nxtDirect) { WAITVM8; } else { WAITVM0; }   // glds(t) landed
    WAITLGKM;                              // ds_writes visible
    SCHEDB;
    __builtin_amdgcn_s_barrier();
    // ---- compute phase ----
#pragma unroll
    for (int kk = 0; kk < 2; ++kk) {
      bf16x8 af[4], bv[4];
#pragma unroll
      for (int m = 0; m < 4; ++m) af[m] = *(const bf16x8*)(smem + offA[kk][m]);
#pragma unroll
      for (int n = 0; n < 4; ++n) bv[n] = *(const bf16x8*)(smem + offB[kk][n]);
      __builtin_amdgcn_s_setprio(1);
#pragma unroll
      for (int m = 0; m < 4; ++m)
#pragma unroll
        for (int n = 0; n < 4; ++n)
          acc[m][n] = __builtin_amdgcn_mfma_f32_16x16x32_bf16(af[m], bv[n], acc[m][n], 0, 0, 0);
      __builtin_amdgcn_s_setprio(0);
    }
    __builtin_amdgcn_s_barrier();
  }

  // --- epilogue: bias, store, optional fused group stats ---
  const int cr = (lane >> 4) << 2;
  const int cc = lane & 15;
  float sacc[4] = {0, 0, 0, 0}, qacc[4] = {0, 0, 0, 0};
#pragma unroll
  for (int n = 0; n < 4; ++n) {
    const int colg = col0 + wn * 64 + n * 16 + cc;
    const float bvv = bias[colg];
#pragma unroll
    for (int m = 0; m < 4; ++m) {
      const int rowg = row0 + wm * 64 + m * 16 + cr;
#pragma unroll
      for (int r2 = 0; r2 < 4; ++r2) {
        const float v = acc[m][n][r2] + bvv;
        if constexpr (STATS) { sacc[n] += v; qacc[n] += v * v; }
        if constexpr (EPI == 0)
          ((ushort*)Cout)[(size_t)(rowg + r2) * N + colg] = f2bf(v);
        else
          ((float*)Cout)[(size_t)(rowg + r2) * N + colg] = v;
      }
    }
  }
  if constexpr (STATS) {
    const int gsize = N >> 5;
#pragma unroll
    for (int n = 0; n < 4; ++n) {
      float s = sacc[n], q = qacc[n];
      s += __shfl_xor(s, 16); q += __shfl_xor(q, 16);
      s += __shfl_xor(s, 32); q += __shfl_xor(q, 32);
      if (lane < 16) {
        const int colg = col0 + wn * 64 + n * 16 + lane;
        const int g = colg / gsize;
        atomicAdd(&ssum[g], s);
        atomicAdd(&ssq[g], q);
      }
    }
    __syncthreads();
    if (tid < 32) {
      const int g0 = col0 / gsize, g1 = (col0 + BN) / gsize;
      if (tid >= g0 && tid < g1) {
        atomicAdd(&stats[2 * tid], ssum[tid]);
        atomicAdd(&stats[2 * tid + 1], ssq[tid]);
      }
    }
  }
}

// ---------- host ----------
extern "C" void kernel_launch(void* const* d_in, const int* in_sizes, int n_in,
                              void* d_out, int out_size, void* d_ws, size_t ws_size,
                              hipStream_t stream) {
  const float* s2   = (const float*)d_in[0];   // (131072, 256)
  const float* s3   = (const float*)d_in[1];   // (32768, 512)
  const float* s4   = (const float*)d_in[2];   // (8192, 1024)
  const float* s5   = (const float*)d_in[3];   // (2048, 2048)
  const int*   up1  = (const int*)d_in[4];
  const int*   up2  = (const int*)d_in[5];
  const int*   up3  = (const int*)d_in[6];
  const float* W_in = (const float*)d_in[7];   // (2048, 2048)
  const float* b_in = (const float*)d_in[8];
  const float* W4   = (const float*)d_in[9];   // (1024, 3072)
  const float* b4   = (const float*)d_in[10];
  const float* g4   = (const float*)d_in[11];
  const float* bt4  = (const float*)d_in[12];
  const float* W3   = (const float*)d_in[13];  // (512, 1536)
  const float* b3   = (const float*)d_in[14];
  const float* g3   = (const float*)d_in[15];
  const float* bt3  = (const float*)d_in[16];
  const float* W2   = (const float*)d_in[17];  // (256, 768)
  const float* b2   = (const float*)d_in[18];
  float* out = (float*)d_out;
  char* ws = (char*)d_ws;

  // Workspace layout (~126 MB)
  ushort* Winb  = (ushort*)(ws + 0);          //  8.39 MB
  ushort* W4b   = (ushort*)(ws + 8388608);    //  6.29 MB
  ushort* W3b   = (ushort*)(ws + 14680064);   //  1.57 MB
  ushort* W2b   = (ushort*)(ws + 16252928);   //  0.39 MB
  float*  stats = (float*)(ws + 16646144);    //  512 B
  ushort* x5b   = (ushort*)(ws + 16777216);   //  8.39 MB (2048x2048)
  ushort* l4lin = (ushort*)(ws + 25165824);   // 16.78 MB (8192x1024)
  ushort* l4b   = (ushort*)(ws + 41943040);   // 16.78 MB
  ushort* l3lin = (ushort*)(ws + 58720256);   // 33.55 MB (32768x512)
  ushort* l3b   = (ushort*)(ws + 92274688);   // 33.55 MB

  zero_kernel<<<1, 128, 0, stream>>>(stats);

  // convert weights only
  CvtArgs ca;
  const float* srcs[4] = { W_in, W4, W3, W2 };
  ushort* dsts[4] = { Winb, W4b, W3b, W2b };
  long ns[4] = { 2048L*2048, 1024L*3072, 512L*1536, 256L*768 };
  int cum = 0;
  for (int i = 0; i < 4; ++i) {
    ca.seg[i].src = (const f32x4*)srcs[i];
    ca.seg[i].dst = (u32x4*)dsts[i];
    ca.start[i] = cum;
    cum += (int)(ns[i] >> 3);
  }
  ca.start[4] = cum;
  cvt_multi<<<1024, 256, 0, stream>>>(ca, cum);

  // x5 = s5(f32 direct) @ W_in^T + b_in (2048x2048, K=2048)  grid 16x16=256
  gemms<0, 0><<<256, 256, 0, stream>>>(
      nullptr, s5, nullptr, 0, Winb, b_in, x5b, nullptr, 2048, 2048, 2048);
  // l4lin = concat(x5b[up3] DMA, s4 f32) @ W4^T + b4, stats fused (8192x1024,K=3072) grid 64x8=512
  gemms<0, 1><<<512, 256, 0, stream>>>(
      x5b, s4, up3, 2048, W4b, b4, l4lin, stats, 8192, 1024, 3072);
  gn_apply<<<2048, 256, 0, stream>>>(l4lin, stats, g4, bt4, l4b, 8192, 1024,
                                     1.0f / 262144.0f);
  // l3lin = concat(l4b[up2] DMA, s3 f32) @ W3^T + b3, stats fused (32768x512,K=1536) grid 256x4=1024
  gemms<0, 1><<<1024, 256, 0, stream>>>(
      l4b, s3, up2, 1024, W3b, b3, l3lin, stats + 64, 32768, 512, 1536);
  gn_apply<<<2048, 256, 0, stream>>>(l3lin, stats + 64, g3, bt3, l3b, 32768, 512,
                                     1.0f / 524288.0f);
  // out = concat(l3b[up1] DMA, s2 f32) @ W2^T + b2 -> f32 (131072x256,K=768) grid 1024x2=2048
  gemms<1, 0><<<2048, 256, 0, stream>>>(
      l3b, s2, up1, 512, W2b, b2, out, nullptr, 131072, 256, 768);

  (void)in_sizes; (void)n_in; (void)out_size; (void)ws_size;
}